// Round 1
// baseline (418.656 us; speedup 1.0000x reference)
//
#include <hip/hip_runtime.h>
#include <hip/hip_bf16.h>

// Problem constants
static constexpr int kN   = 4096;   // tokens
static constexpr int kIn  = 128;    // input dim
static constexpr int kHid = 512;    // hidden
static constexpr int kH   = 8;      // heads
static constexpr int kD   = 64;     // head dim
#define NEGV (-1e9f)

typedef __bf16 bf16x8 __attribute__((ext_vector_type(8)));
typedef float  f32x4  __attribute__((ext_vector_type(4)));

__device__ __forceinline__ unsigned short f2bf(float f) {
    return __builtin_bit_cast(unsigned short, (__bf16)f);
}

// ---------------- mask dtype detection ----------------
// bool mask may arrive as int32 (0/1), uint8 (0/1), or f32 (0.0/1.0).
// Scan first 4096 words: f32 shows 0x3F800000; uint8-packed shows words >1.
__global__ void detect_mask_kernel(const unsigned int* __restrict__ m, int* __restrict__ mode) {
    int t = threadIdx.x;
    int isf = 0, isb = 0;
    for (int i = t; i < 4096; i += 64) {
        unsigned int w = m[i];
        if (w == 0x3F800000u) isf = 1;
        else if (w > 1u)      isb = 1;
    }
    unsigned long long bf = __ballot(isf != 0);
    unsigned long long bb = __ballot(isb != 0);
    if (t == 0) mode[0] = bf ? 2 : (bb ? 1 : 0);
}

// ---------------- weight transpose f32[R][C] -> bf16[C][R] ----------------
__global__ void transpose_w_kernel(const float* __restrict__ src, unsigned short* __restrict__ dst,
                                   int R, int C) {
    __shared__ float t[32][33];
    int c0 = blockIdx.x * 32, r0 = blockIdx.y * 32;
    int tx = threadIdx.x, ty = threadIdx.y;
#pragma unroll
    for (int i = 0; i < 4; i++) {
        int r = ty + i * 8;
        t[r][tx] = src[(size_t)(r0 + r) * C + c0 + tx];
    }
    __syncthreads();
#pragma unroll
    for (int i = 0; i < 4; i++) {
        int r = ty + i * 8;
        dst[(size_t)(c0 + r) * R + r0 + tx] = f2bf(t[tx][r]);
    }
}

// ---------------- GEMM: C[M,N] = A[M,K] @ Bt[N,K]^T + bias ----------------
// ABF: A is bf16 (else f32, converted on stage). OBF: out bf16 (else f32).
// WT:  write transposed C[n*M + m] (bf16) — used to produce V^T.
template <bool ABF, bool OBF, bool WT>
__global__ __launch_bounds__(256) void gemm_kernel(const void* __restrict__ Ap,
                                                   const unsigned short* __restrict__ Bt,
                                                   const float* __restrict__ bias,
                                                   void* __restrict__ Cp,
                                                   int M, int Nn, int K) {
    __shared__ unsigned short As[128][40];
    __shared__ unsigned short Bs[128][40];
    const int tid  = threadIdx.x;
    const int lane = tid & 63;
    const int wv   = tid >> 6;
    const int wr   = wv >> 1, wc = wv & 1;
    const int m0 = blockIdx.x * 128, n0 = blockIdx.y * 128;
    const int g = lane >> 4, li = lane & 15;

    f32x4 acc[4][4] = {};
    const int rr = tid >> 2;
    const int cc = (tid & 3) * 8;

    for (int k0 = 0; k0 < K; k0 += 32) {
#pragma unroll
        for (int p = 0; p < 128; p += 64) {
            int r = rr + p;
            if (ABF) {
                const unsigned short* A = (const unsigned short*)Ap;
                *(uint4*)&As[r][cc] = *(const uint4*)(A + (size_t)(m0 + r) * K + k0 + cc);
            } else {
                const float* A = (const float*)Ap;
                const float4 v0 = *(const float4*)(A + (size_t)(m0 + r) * K + k0 + cc);
                const float4 v1 = *(const float4*)(A + (size_t)(m0 + r) * K + k0 + cc + 4);
                uint4 u;
                u.x = f2bf(v0.x) | ((unsigned)f2bf(v0.y) << 16);
                u.y = f2bf(v0.z) | ((unsigned)f2bf(v0.w) << 16);
                u.z = f2bf(v1.x) | ((unsigned)f2bf(v1.y) << 16);
                u.w = f2bf(v1.z) | ((unsigned)f2bf(v1.w) << 16);
                *(uint4*)&As[r][cc] = u;
            }
            *(uint4*)&Bs[r][cc] = *(const uint4*)(Bt + (size_t)(n0 + r) * K + k0 + cc);
        }
        __syncthreads();

        bf16x8 af[4], bf[4];
#pragma unroll
        for (int mi = 0; mi < 4; mi++)
            af[mi] = *(const bf16x8*)&As[wr * 64 + mi * 16 + li][g * 8];
#pragma unroll
        for (int ni = 0; ni < 4; ni++)
            bf[ni] = *(const bf16x8*)&Bs[wc * 64 + ni * 16 + li][g * 8];
#pragma unroll
        for (int mi = 0; mi < 4; mi++)
#pragma unroll
            for (int ni = 0; ni < 4; ni++)
                acc[mi][ni] = __builtin_amdgcn_mfma_f32_16x16x32_bf16(af[mi], bf[ni], acc[mi][ni], 0, 0, 0);
        __syncthreads();
    }

#pragma unroll
    for (int mi = 0; mi < 4; mi++) {
        int rowb = m0 + wr * 64 + mi * 16 + g * 4;
#pragma unroll
        for (int ni = 0; ni < 4; ni++) {
            int col = n0 + wc * 64 + ni * 16 + li;
            float bv = bias ? bias[col] : 0.f;
            if (WT) {
                unsigned short* C = (unsigned short*)Cp;
                ushort4 st;
                st.x = f2bf(acc[mi][ni][0] + bv);
                st.y = f2bf(acc[mi][ni][1] + bv);
                st.z = f2bf(acc[mi][ni][2] + bv);
                st.w = f2bf(acc[mi][ni][3] + bv);
                *(ushort4*)(C + (size_t)col * M + rowb) = st;
            } else if (OBF) {
                unsigned short* C = (unsigned short*)Cp;
#pragma unroll
                for (int r2 = 0; r2 < 4; r2++)
                    C[(size_t)(rowb + r2) * Nn + col] = f2bf(acc[mi][ni][r2] + bv);
            } else {
                float* C = (float*)Cp;
#pragma unroll
                for (int r2 = 0; r2 < 4; r2++)
                    C[(size_t)(rowb + r2) * Nn + col] = acc[mi][ni][r2] + bv;
            }
        }
    }
}

// ---------------- fused multi-head attention (flash-style, split-K) ----------------
// grid: 256 blocks = (qtile 0..127) x (z half 0..1); block: 512 threads = 8 waves, wave = head.
// Bias tile (mask*NEG + tb) staged in LDS once per k-tile, shared by all heads.
__global__ __launch_bounds__(512) void attn_kernel(
    const unsigned short* __restrict__ qg, const unsigned short* __restrict__ kg,
    const unsigned short* __restrict__ vt, const void* __restrict__ maskp,
    const float* __restrict__ tb, const int* __restrict__ modep,
    float* __restrict__ Op, float* __restrict__ Mp, float* __restrict__ Lp) {
    __shared__ float bias_s[32][33];
    __shared__ unsigned short p_s[8][32][40];

    const int tid  = threadIdx.x;
    const int lane = tid & 63;
    const int w    = tid >> 6;        // head
    const int qt   = blockIdx.x >> 1;
    const int z    = blockIdx.x & 1;
    const int n0   = qt * 32;
    const int mode = modep[0];
    const int g = lane >> 4, li = lane & 15;

    // Q fragments (resident)
    bf16x8 qa[2][2];
#pragma unroll
    for (int qi = 0; qi < 2; qi++)
#pragma unroll
        for (int ks = 0; ks < 2; ks++)
            qa[qi][ks] = *(const bf16x8*)(qg + (size_t)(n0 + qi * 16 + li) * kHid + w * kD + ks * 32 + g * 8);

    f32x4 po[2][4] = {};
    float m_run[2][4], l_run[2][4];
#pragma unroll
    for (int qi = 0; qi < 2; qi++)
#pragma unroll
        for (int r = 0; r < 4; r++) { m_run[qi][r] = -1e30f; l_run[qi][r] = 0.f; }

    const int br = tid >> 4;          // bias row 0..31
    const int bc = (tid & 15) * 2;    // bias col pair

    for (int kt = 0; kt < 64; kt++) {
        const int m0k = z * 2048 + kt * 32;
        __syncthreads();
        {   // stage bias tile
            size_t idx = (size_t)(n0 + br) * kN + m0k + bc;
            float2 tv = *(const float2*)(tb + idx);
            bool x0, x1;
            if (mode == 0) {
                const int* mp = (const int*)maskp;
                int2 v = *(const int2*)(mp + idx);
                x0 = v.x != 0; x1 = v.y != 0;
            } else if (mode == 1) {
                const unsigned char* mp = (const unsigned char*)maskp;
                x0 = mp[idx] != 0; x1 = mp[idx + 1] != 0;
            } else {
                const float* mp = (const float*)maskp;
                float2 v = *(const float2*)(mp + idx);
                x0 = v.x != 0.f; x1 = v.y != 0.f;
            }
            bias_s[br][bc]     = (x0 ? NEGV : 0.f) + tv.x;
            bias_s[br][bc + 1] = (x1 ? NEGV : 0.f) + tv.y;
        }
        __syncthreads();

        // QK^T for this head
        f32x4 sc[2][2] = {};
#pragma unroll
        for (int mj = 0; mj < 2; mj++) {
            bf16x8 kb[2];
#pragma unroll
            for (int ks = 0; ks < 2; ks++)
                kb[ks] = *(const bf16x8*)(kg + (size_t)(m0k + mj * 16 + li) * kHid + w * kD + ks * 32 + g * 8);
#pragma unroll
            for (int qi = 0; qi < 2; qi++)
#pragma unroll
                for (int ks = 0; ks < 2; ks++)
                    sc[qi][mj] = __builtin_amdgcn_mfma_f32_16x16x32_bf16(qa[qi][ks], kb[ks], sc[qi][mj], 0, 0, 0);
        }

        // online softmax (rows are lane-resident: row = qi*16 + g*4 + r)
#pragma unroll
        for (int qi = 0; qi < 2; qi++) {
#pragma unroll
            for (int r = 0; r < 4; r++) {
                int row = qi * 16 + g * 4 + r;
                float v0 = sc[qi][0][r] * 0.125f + bias_s[row][li];
                float v1 = sc[qi][1][r] * 0.125f + bias_s[row][16 + li];
                float mx = fmaxf(v0, v1);
                mx = fmaxf(mx, __shfl_xor(mx, 1));
                mx = fmaxf(mx, __shfl_xor(mx, 2));
                mx = fmaxf(mx, __shfl_xor(mx, 4));
                mx = fmaxf(mx, __shfl_xor(mx, 8));
                float mold = m_run[qi][r];
                float mnew = fmaxf(mold, mx);
                float alpha = __expf(mold - mnew);
                m_run[qi][r] = mnew;
                float p0 = __expf(v0 - mnew);
                float p1 = __expf(v1 - mnew);
                float rs = p0 + p1;
                rs += __shfl_xor(rs, 1);
                rs += __shfl_xor(rs, 2);
                rs += __shfl_xor(rs, 4);
                rs += __shfl_xor(rs, 8);
                l_run[qi][r] = l_run[qi][r] * alpha + rs;
#pragma unroll
                for (int nj = 0; nj < 4; nj++) po[qi][nj][r] *= alpha;
                p_s[w][row][li]      = f2bf(p0);
                p_s[w][row][16 + li] = f2bf(p1);
            }
        }

        // PV (intra-wave LDS RAW: DS ops are in-order per wave)
        bf16x8 pa[2];
        pa[0] = *(const bf16x8*)&p_s[w][li][g * 8];
        pa[1] = *(const bf16x8*)&p_s[w][16 + li][g * 8];
#pragma unroll
        for (int nj = 0; nj < 4; nj++) {
            bf16x8 vb = *(const bf16x8*)(vt + (size_t)(w * kD + nj * 16 + li) * kN + m0k + g * 8);
#pragma unroll
            for (int qi = 0; qi < 2; qi++)
                po[qi][nj] = __builtin_amdgcn_mfma_f32_16x16x32_bf16(pa[qi], vb, po[qi][nj], 0, 0, 0);
        }
    }

    // write split-K partials
#pragma unroll
    for (int qi = 0; qi < 2; qi++) {
#pragma unroll
        for (int nj = 0; nj < 4; nj++) {
#pragma unroll
            for (int r = 0; r < 4; r++) {
                int row = n0 + qi * 16 + g * 4 + r;
                Op[(((size_t)z * kN + row) * kH + w) * kD + nj * 16 + li] = po[qi][nj][r];
            }
        }
    }
    if (li == 0) {
#pragma unroll
        for (int qi = 0; qi < 2; qi++)
#pragma unroll
            for (int r = 0; r < 4; r++) {
                int row = n0 + qi * 16 + g * 4 + r;
                Mp[((size_t)z * kN + row) * kH + w] = m_run[qi][r];
                Lp[((size_t)z * kN + row) * kH + w] = l_run[qi][r];
            }
    }
}

// ---------------- split-K combine -> xo bf16[N][Hid] ----------------
__global__ __launch_bounds__(256) void combine_kernel(const float* __restrict__ Op,
                                                      const float* __restrict__ Mp,
                                                      const float* __restrict__ Lp,
                                                      unsigned short* __restrict__ xo) {
    int idx = blockIdx.x * 256 + threadIdx.x;
    int n = idx >> 9, c = idx & 511;
    int h = c >> 6, d = c & 63;
    float m0 = Mp[(size_t)n * kH + h], m1 = Mp[(size_t)(kN + n) * kH + h];
    float l0 = Lp[(size_t)n * kH + h], l1 = Lp[(size_t)(kN + n) * kH + h];
    float mm = fmaxf(m0, m1);
    float a0 = __expf(m0 - mm), a1 = __expf(m1 - mm);
    float o0 = Op[((size_t)n * kH + h) * kD + d];
    float o1 = Op[((size_t)(kN + n) * kH + h) * kD + d];
    xo[idx] = f2bf((o0 * a0 + o1 * a1) / (l0 * a0 + l1 * a1));
}

// ---------------- launch ----------------
extern "C" void kernel_launch(void* const* d_in, const int* in_sizes, int n_in,
                              void* d_out, int out_size, void* d_ws, size_t ws_size,
                              hipStream_t stream) {
    const float* node = (const float*)d_in[0];
    const void*  mask = d_in[1];
    const float* tb   = (const float*)d_in[2];
    const float* W_in = (const float*)d_in[3];
    const float* b_in = (const float*)d_in[4];
    const float* Wq   = (const float*)d_in[5];
    const float* bq   = (const float*)d_in[6];
    const float* Wk   = (const float*)d_in[7];
    const float* bk   = (const float*)d_in[8];
    const float* Wv   = (const float*)d_in[9];
    const float* bv   = (const float*)d_in[10];
    const float* Wo   = (const float*)d_in[11];
    const float* bo   = (const float*)d_in[12];

    char* ws = (char*)d_ws;
    size_t off = 0;
    auto alloc = [&](size_t bytes) {
        void* p = ws + off;
        off += (bytes + 255) & ~(size_t)255;
        return p;
    };
    unsigned short* x    = (unsigned short*)alloc((size_t)kN * kHid * 2);
    unsigned short* q    = (unsigned short*)alloc((size_t)kN * kHid * 2);
    unsigned short* kbuf = (unsigned short*)alloc((size_t)kN * kHid * 2);
    unsigned short* vt   = (unsigned short*)alloc((size_t)kHid * kN * 2);
    unsigned short* xo   = (unsigned short*)alloc((size_t)kN * kHid * 2);
    unsigned short* Wt_in = (unsigned short*)alloc((size_t)kHid * kIn * 2);
    unsigned short* Wt_q  = (unsigned short*)alloc((size_t)kHid * kHid * 2);
    unsigned short* Wt_k  = (unsigned short*)alloc((size_t)kHid * kHid * 2);
    unsigned short* Wt_v  = (unsigned short*)alloc((size_t)kHid * kHid * 2);
    unsigned short* Wt_o  = (unsigned short*)alloc((size_t)kHid * kHid * 2);
    float* Op = (float*)alloc((size_t)2 * kN * kH * kD * 4);
    float* Mp = (float*)alloc((size_t)2 * kN * kH * 4);
    float* Lp = (float*)alloc((size_t)2 * kN * kH * 4);
    int*   mode = (int*)alloc(256);
    (void)ws_size; (void)in_sizes; (void)n_in; (void)out_size;

    detect_mask_kernel<<<1, 64, 0, stream>>>((const unsigned int*)mask, mode);

    transpose_w_kernel<<<dim3(kHid / 32, kIn / 32), dim3(32, 8), 0, stream>>>(W_in, Wt_in, kIn, kHid);
    transpose_w_kernel<<<dim3(kHid / 32, kHid / 32), dim3(32, 8), 0, stream>>>(Wq, Wt_q, kHid, kHid);
    transpose_w_kernel<<<dim3(kHid / 32, kHid / 32), dim3(32, 8), 0, stream>>>(Wk, Wt_k, kHid, kHid);
    transpose_w_kernel<<<dim3(kHid / 32, kHid / 32), dim3(32, 8), 0, stream>>>(Wv, Wt_v, kHid, kHid);
    transpose_w_kernel<<<dim3(kHid / 32, kHid / 32), dim3(32, 8), 0, stream>>>(Wo, Wt_o, kHid, kHid);

    // x = node @ W_in + b_in   (f32 A)
    gemm_kernel<false, true, false><<<dim3(kN / 128, kHid / 128), 256, 0, stream>>>(
        node, Wt_in, b_in, x, kN, kHid, kIn);
    // q,k
    gemm_kernel<true, true, false><<<dim3(kN / 128, kHid / 128), 256, 0, stream>>>(
        x, Wt_q, bq, q, kN, kHid, kHid);
    gemm_kernel<true, true, false><<<dim3(kN / 128, kHid / 128), 256, 0, stream>>>(
        x, Wt_k, bk, kbuf, kN, kHid, kHid);
    // v, written transposed -> vt[512][4096]
    gemm_kernel<true, true, true><<<dim3(kN / 128, kHid / 128), 256, 0, stream>>>(
        x, Wt_v, bv, vt, kN, kHid, kHid);

    attn_kernel<<<256, 512, 0, stream>>>(q, kbuf, vt, mask, tb, mode, Op, Mp, Lp);
    combine_kernel<<<(kN * kHid) / 256, 256, 0, stream>>>(Op, Mp, Lp, xo);

    // out = xo @ Wo + bo  (f32 out)
    gemm_kernel<true, false, false><<<dim3(kN / 128, kHid / 128), 256, 0, stream>>>(
        xo, Wt_o, bo, (float*)d_out, kN, kHid, kHid);
}

// Round 2
// 231.796 us; speedup vs baseline: 1.8061x; 1.8061x over previous
//
#include <hip/hip_runtime.h>
#include <hip/hip_bf16.h>

static constexpr int kN   = 4096;
static constexpr int kIn  = 128;
static constexpr int kHid = 512;
static constexpr int kH   = 8;
static constexpr int kD   = 64;
#define NEGV (-1e9f)

typedef __bf16 bf16x8 __attribute__((ext_vector_type(8)));
typedef float  f32x4  __attribute__((ext_vector_type(4)));
typedef float  f32x16 __attribute__((ext_vector_type(16)));

__device__ __forceinline__ unsigned short f2bf(float f) {
    return __builtin_bit_cast(unsigned short, (__bf16)f);
}
__device__ __forceinline__ unsigned pkbf(float a, float b) {
    return (unsigned)f2bf(a) | ((unsigned)f2bf(b) << 16);
}

// ---------------- mask dtype detection ----------------
__global__ void detect_mask_kernel(const unsigned int* __restrict__ m, int* __restrict__ mode) {
    int t = threadIdx.x;
    int isf = 0, isb = 0;
    for (int i = t; i < 4096; i += 64) {
        unsigned int w = m[i];
        if (w == 0x3F800000u) isf = 1;
        else if (w > 1u)      isb = 1;
    }
    unsigned long long bf = __ballot(isf != 0);
    unsigned long long bb = __ballot(isb != 0);
    if (t == 0) mode[0] = bf ? 2 : (bb ? 1 : 0);
}

// ---------------- weight transpose f32[R][C] -> bf16[C][R] ----------------
__global__ void transpose_w_kernel(const float* __restrict__ src, unsigned short* __restrict__ dst,
                                   int R, int C) {
    __shared__ float t[32][33];
    int c0 = blockIdx.x * 32, r0 = blockIdx.y * 32;
    int tx = threadIdx.x, ty = threadIdx.y;
#pragma unroll
    for (int i = 0; i < 4; i++) {
        int r = ty + i * 8;
        t[r][tx] = src[(size_t)(r0 + r) * C + c0 + tx];
    }
    __syncthreads();
#pragma unroll
    for (int i = 0; i < 4; i++) {
        int r = ty + i * 8;
        dst[(size_t)(c0 + r) * R + r0 + tx] = f2bf(t[tx][r]);
    }
}

__global__ void concat_bias_kernel(const float* __restrict__ bq, const float* __restrict__ bk,
                                   const float* __restrict__ bv, float* __restrict__ dst) {
    int i = blockIdx.x * 256 + threadIdx.x;
    if (i < 1536)
        dst[i] = i < 512 ? bq[i] : (i < 1024 ? bk[i - 512] : bv[i - 1024]);
}

// ---------------- GEMM: C[M,N] = A[M,K] @ Bt[N,K]^T + bias ----------------
// OMODE 0: f32 out (stride ldc). 1: bf16 out (stride ldc).
// 3: fused-QKV: col<1024 -> bf16 Cp[row*ldc+col]; col>=1024 -> bf16 transposed Cp2[(col-1024)*M+row].
template <bool ABF, int OMODE>
__global__ __launch_bounds__(256) void gemm_kernel(const void* __restrict__ Ap,
                                                   const unsigned short* __restrict__ Bt,
                                                   const float* __restrict__ bias,
                                                   void* __restrict__ Cp, void* __restrict__ Cp2,
                                                   int M, int Nn, int K, int ldc) {
    __shared__ unsigned short As[128][40];
    __shared__ unsigned short Bs[128][40];
    const int tid  = threadIdx.x;
    const int lane = tid & 63;
    const int wv   = tid >> 6;
    const int wr   = wv >> 1, wc = wv & 1;
    const int m0 = blockIdx.x * 128, n0 = blockIdx.y * 128;
    const int g = lane >> 4, li = lane & 15;

    f32x4 acc[4][4] = {};
    const int rr = tid >> 2;
    const int cc = (tid & 3) * 8;

    for (int k0 = 0; k0 < K; k0 += 32) {
#pragma unroll
        for (int p = 0; p < 128; p += 64) {
            int r = rr + p;
            if (ABF) {
                const unsigned short* A = (const unsigned short*)Ap;
                *(uint4*)&As[r][cc] = *(const uint4*)(A + (size_t)(m0 + r) * K + k0 + cc);
            } else {
                const float* A = (const float*)Ap;
                const float4 v0 = *(const float4*)(A + (size_t)(m0 + r) * K + k0 + cc);
                const float4 v1 = *(const float4*)(A + (size_t)(m0 + r) * K + k0 + cc + 4);
                uint4 u;
                u.x = f2bf(v0.x) | ((unsigned)f2bf(v0.y) << 16);
                u.y = f2bf(v0.z) | ((unsigned)f2bf(v0.w) << 16);
                u.z = f2bf(v1.x) | ((unsigned)f2bf(v1.y) << 16);
                u.w = f2bf(v1.z) | ((unsigned)f2bf(v1.w) << 16);
                *(uint4*)&As[r][cc] = u;
            }
            *(uint4*)&Bs[r][cc] = *(const uint4*)(Bt + (size_t)(n0 + r) * K + k0 + cc);
        }
        __syncthreads();

        bf16x8 af[4], bfv[4];
#pragma unroll
        for (int mi = 0; mi < 4; mi++)
            af[mi] = *(const bf16x8*)&As[wr * 64 + mi * 16 + li][g * 8];
#pragma unroll
        for (int ni = 0; ni < 4; ni++)
            bfv[ni] = *(const bf16x8*)&Bs[wc * 64 + ni * 16 + li][g * 8];
#pragma unroll
        for (int mi = 0; mi < 4; mi++)
#pragma unroll
            for (int ni = 0; ni < 4; ni++)
                acc[mi][ni] = __builtin_amdgcn_mfma_f32_16x16x32_bf16(af[mi], bfv[ni], acc[mi][ni], 0, 0, 0);
        __syncthreads();
    }

#pragma unroll
    for (int mi = 0; mi < 4; mi++) {
        int rowb = m0 + wr * 64 + mi * 16 + g * 4;
#pragma unroll
        for (int ni = 0; ni < 4; ni++) {
            int col = n0 + wc * 64 + ni * 16 + li;
            float bv = bias ? bias[col] : 0.f;
            if (OMODE == 3) {
                if (col < 1024) {
                    unsigned short* C = (unsigned short*)Cp;
#pragma unroll
                    for (int r2 = 0; r2 < 4; r2++)
                        C[(size_t)(rowb + r2) * ldc + col] = f2bf(acc[mi][ni][r2] + bv);
                } else {
                    unsigned short* C = (unsigned short*)Cp2;
                    ushort4 st;
                    st.x = f2bf(acc[mi][ni][0] + bv);
                    st.y = f2bf(acc[mi][ni][1] + bv);
                    st.z = f2bf(acc[mi][ni][2] + bv);
                    st.w = f2bf(acc[mi][ni][3] + bv);
                    *(ushort4*)(C + (size_t)(col - 1024) * M + rowb) = st;
                }
            } else if (OMODE == 1) {
                unsigned short* C = (unsigned short*)Cp;
#pragma unroll
                for (int r2 = 0; r2 < 4; r2++)
                    C[(size_t)(rowb + r2) * ldc + col] = f2bf(acc[mi][ni][r2] + bv);
            } else {
                float* C = (float*)Cp;
#pragma unroll
                for (int r2 = 0; r2 < 4; r2++)
                    C[(size_t)(rowb + r2) * ldc + col] = acc[mi][ni][r2] + bv;
            }
        }
    }
}

// ---------------- fused attention, swapped-QK^T 32x32, split-K over z ----------------
// grid (128, NZ); block 512 = 8 waves, wave = head.
// qkbuf: [4096][1024] bf16 (q cols 0..511, k cols 512..1023); vt: [512][4096] bf16.
// Per lane: query q5 = lane&31; scores C[key][q]: lane holds 16 keys of its query.
__global__ __launch_bounds__(512) void attn_kernel(
    const unsigned short* __restrict__ qk, const unsigned short* __restrict__ vt,
    const void* __restrict__ maskp, const float* __restrict__ tb,
    const int* __restrict__ modep,
    float* __restrict__ Op, float* __restrict__ Mp, float* __restrict__ Lp,
    int KZ, int NC) {
    __shared__ float bias_s[2][128][33];   // [buf][key][q], transposed, conflict-free

    const int tid  = threadIdx.x;
    const int lane = tid & 63;
    const int w    = tid >> 6;
    const int q5   = lane & 31;
    const int hi   = lane >> 5;
    const int n0   = blockIdx.x * 32;
    const int z    = blockIdx.y;
    const int kz0  = z * KZ;
    const int mode = modep[0];
    const int hb   = w * kD;

    // Q fragments (B-operand, resident): frag f covers d = f*16 + hi*8 + j
    bf16x8 qf[4];
#pragma unroll
    for (int f = 0; f < 4; f++)
        qf[f] = *(const bf16x8*)(qk + (size_t)(n0 + q5) * 1024 + hb + f * 16 + hi * 8);

    f32x16 po[2] = {};
    float m_run = -3e38f, l_run = 0.f;

    // staging mapping: thread -> (q-row sr, colgroup scg of 8 keys)
    const int sr  = tid & 31;
    const int scg = tid >> 5;
    float stg[8];

    auto stage_load = [&](int kbase) {
        size_t idx = (size_t)(n0 + sr) * kN + kbase + scg * 8;
        float tv[8];
        *(float4*)&tv[0] = *(const float4*)(tb + idx);
        *(float4*)&tv[4] = *(const float4*)(tb + idx + 4);
        if (mode == 0) {
            const int* mp = (const int*)maskp;
            int4 a = *(const int4*)(mp + idx);
            int4 b = *(const int4*)(mp + idx + 4);
            int mv[8] = {a.x, a.y, a.z, a.w, b.x, b.y, b.z, b.w};
#pragma unroll
            for (int j = 0; j < 8; j++) stg[j] = (mv[j] ? NEGV : 0.f) + tv[j];
        } else if (mode == 1) {
            const unsigned char* mp = (const unsigned char*)maskp;
            uint2 u = *(const uint2*)(mp + idx);
#pragma unroll
            for (int j = 0; j < 4; j++) stg[j] = (((u.x >> (8 * j)) & 255u) ? NEGV : 0.f) + tv[j];
#pragma unroll
            for (int j = 0; j < 4; j++) stg[4 + j] = (((u.y >> (8 * j)) & 255u) ? NEGV : 0.f) + tv[4 + j];
        } else {
            const float* mp = (const float*)maskp;
            float4 a = *(const float4*)(mp + idx);
            float4 b = *(const float4*)(mp + idx + 4);
            float mv[8] = {a.x, a.y, a.z, a.w, b.x, b.y, b.z, b.w};
#pragma unroll
            for (int j = 0; j < 8; j++) stg[j] = (mv[j] != 0.f ? NEGV : 0.f) + tv[j];
        }
    };
    auto stage_write = [&](int buf) {
#pragma unroll
        for (int j = 0; j < 8; j++) bias_s[buf][scg * 8 + j][sr] = stg[j];
    };

    stage_load(kz0);
    stage_write(0);
    __syncthreads();

    for (int c = 0; c < NC; c++) {
        if (c + 1 < NC) stage_load(kz0 + (c + 1) * 128);   // prefetch next chunk (overlaps compute)
        const int cb = c & 1;
#pragma unroll
        for (int s = 0; s < 4; s++) {
            const int kpos = kz0 + c * 128 + s * 32;
            // QK^T (swapped): scores C[key][q]
            f32x16 sc = {};
#pragma unroll
            for (int f = 0; f < 4; f++) {
                bf16x8 kf = *(const bf16x8*)(qk + (size_t)(kpos + q5) * 1024 + 512 + hb + f * 16 + hi * 8);
                sc = __builtin_amdgcn_mfma_f32_32x32x16_bf16(kf, qf[f], sc, 0, 0, 0);
            }
            // bias read (transposed LDS, conflict-free) + scale
            float v[16];
#pragma unroll
            for (int r = 0; r < 16; r++) {
                int key = (r & 3) + 8 * (r >> 2) + 4 * hi;
                v[r] = fmaf(sc[r], 0.125f, bias_s[cb][s * 32 + key][q5]);
            }
            // row max: in-register tree + one cross-half exchange
            float t8[8];
#pragma unroll
            for (int i = 0; i < 8; i++) t8[i] = fmaxf(v[2 * i], v[2 * i + 1]);
#pragma unroll
            for (int i = 0; i < 4; i++) t8[i] = fmaxf(t8[i], t8[i + 4]);
            t8[0] = fmaxf(t8[0], t8[2]); t8[1] = fmaxf(t8[1], t8[3]);
            float mx = fmaxf(t8[0], t8[1]);
            mx = fmaxf(mx, __shfl_xor(mx, 32));
            // online-softmax update with defer-max (THR=8)
            if (!__all(mx <= m_run + 8.0f)) {
                float mnew = fmaxf(m_run, mx);
                float alpha = __expf(m_run - mnew);
                m_run = mnew;
                l_run *= alpha;
                po[0] *= alpha;
                po[1] *= alpha;
            }
            float p[16], s8[8];
#pragma unroll
            for (int i = 0; i < 8; i++) {
                p[2 * i]     = __expf(v[2 * i] - m_run);
                p[2 * i + 1] = __expf(v[2 * i + 1] - m_run);
                s8[i] = p[2 * i] + p[2 * i + 1];
            }
#pragma unroll
            for (int i = 0; i < 4; i++) s8[i] += s8[i + 4];
            s8[0] += s8[2]; s8[1] += s8[3];
            float ssum = s8[0] + s8[1];
            ssum += __shfl_xor(ssum, 32);
            l_run += ssum;
            // repack P -> bf16 B-fragments (keys lane-split by hi)
            unsigned su[8], tu[8];
#pragma unroll
            for (int i = 0; i < 8; i++) su[i] = pkbf(p[2 * i], p[2 * i + 1]);
#pragma unroll
            for (int i = 0; i < 8; i++) tu[i] = __shfl_xor(su[i], 32);
            uint4 f0 = hi ? uint4{tu[2], tu[3], su[2], su[3]} : uint4{su[0], su[1], tu[0], tu[1]};
            uint4 f1 = hi ? uint4{tu[6], tu[7], su[6], su[7]} : uint4{su[4], su[5], tu[4], tu[5]};
            bf16x8 pf0 = __builtin_bit_cast(bf16x8, f0);
            bf16x8 pf1 = __builtin_bit_cast(bf16x8, f1);
            // PV: mfma(V, P) -> C[d][q], query stays lane-local
#pragma unroll
            for (int a = 0; a < 2; a++) {
                const unsigned short* vr = vt + (size_t)(hb + a * 32 + q5) * kN + kpos;
                bf16x8 v0 = *(const bf16x8*)(vr + hi * 8);
                bf16x8 v1 = *(const bf16x8*)(vr + 16 + hi * 8);
                po[a] = __builtin_amdgcn_mfma_f32_32x32x16_bf16(v0, pf0, po[a], 0, 0, 0);
                po[a] = __builtin_amdgcn_mfma_f32_32x32x16_bf16(v1, pf1, po[a], 0, 0, 0);
            }
        }
        if (c + 1 < NC) {
            __syncthreads();
            stage_write((c + 1) & 1);
            __syncthreads();
        }
    }

    // epilogue: split-K partials. Lane holds O[d-rows][its query].
    float* ob = Op + ((((size_t)z * kN + n0 + q5) * kH + w) << 6);
#pragma unroll
    for (int a = 0; a < 2; a++)
#pragma unroll
        for (int m = 0; m < 4; m++) {
            float4 st = {po[a][4 * m], po[a][4 * m + 1], po[a][4 * m + 2], po[a][4 * m + 3]};
            *(float4*)(ob + a * 32 + 8 * m + 4 * hi) = st;
        }
    if (lane < 32) {
        Mp[((size_t)z * kN + n0 + q5) * kH + w] = m_run;
        Lp[((size_t)z * kN + n0 + q5) * kH + w] = l_run;
    }
}

// ---------------- split-K combine -> xo bf16[N][Hid] ----------------
__global__ __launch_bounds__(256) void combine_kernel(const float* __restrict__ Op,
                                                      const float* __restrict__ Mp,
                                                      const float* __restrict__ Lp,
                                                      unsigned short* __restrict__ xo, int NZ) {
    int idx = blockIdx.x * 256 + threadIdx.x;
    int n = idx >> 9, c = idx & 511;
    int h = c >> 6, d = c & 63;
    float m = -3e38f;
    for (int zz = 0; zz < NZ; zz++)
        m = fmaxf(m, Mp[((size_t)zz * kN + n) * kH + h]);
    float num = 0.f, den = 0.f;
    for (int zz = 0; zz < NZ; zz++) {
        float a = __expf(Mp[((size_t)zz * kN + n) * kH + h] - m);
        den += a * Lp[((size_t)zz * kN + n) * kH + h];
        num += a * Op[(((size_t)zz * kN + n) * kH + h) * kD + d];
    }
    xo[idx] = f2bf(num / den);
}

// ---------------- launch ----------------
extern "C" void kernel_launch(void* const* d_in, const int* in_sizes, int n_in,
                              void* d_out, int out_size, void* d_ws, size_t ws_size,
                              hipStream_t stream) {
    const float* node = (const float*)d_in[0];
    const void*  mask = d_in[1];
    const float* tb   = (const float*)d_in[2];
    const float* W_in = (const float*)d_in[3];
    const float* b_in = (const float*)d_in[4];
    const float* Wq   = (const float*)d_in[5];
    const float* bq   = (const float*)d_in[6];
    const float* Wk   = (const float*)d_in[7];
    const float* bk   = (const float*)d_in[8];
    const float* Wv   = (const float*)d_in[9];
    const float* bv   = (const float*)d_in[10];
    const float* Wo   = (const float*)d_in[11];
    const float* bo   = (const float*)d_in[12];
    (void)in_sizes; (void)n_in; (void)out_size;

    char* ws = (char*)d_ws;
    size_t off = 0;
    auto alloc = [&](size_t bytes) {
        void* p = ws + off;
        off += (bytes + 255) & ~(size_t)255;
        return p;
    };
    unsigned short* x     = (unsigned short*)alloc((size_t)kN * kHid * 2);
    unsigned short* qkbuf = (unsigned short*)alloc((size_t)kN * 1024 * 2);
    unsigned short* vt    = (unsigned short*)alloc((size_t)kHid * kN * 2);
    unsigned short* xo    = (unsigned short*)alloc((size_t)kN * kHid * 2);
    unsigned short* Wt_in  = (unsigned short*)alloc((size_t)kHid * kIn * 2);
    unsigned short* Wt_qkv = (unsigned short*)alloc((size_t)3 * kHid * kHid * 2);
    unsigned short* Wt_o   = (unsigned short*)alloc((size_t)kHid * kHid * 2);
    float* bqkv = (float*)alloc(1536 * 4);
    int*   mode = (int*)alloc(256);

    // choose split factor by available workspace
    size_t fixed = off;
    size_t perz = (((size_t)kN * kHid * 4 + 255) & ~(size_t)255) +
                  2 * (((size_t)kN * kH * 4 + 255) & ~(size_t)255);
    int NZ = 4;
    while (NZ > 1 && fixed + (size_t)NZ * perz > ws_size) NZ >>= 1;
    float* Op = (float*)alloc((size_t)NZ * kN * kHid * 4);
    float* Mp = (float*)alloc((size_t)NZ * kN * kH * 4);
    float* Lp = (float*)alloc((size_t)NZ * kN * kH * 4);

    detect_mask_kernel<<<1, 64, 0, stream>>>((const unsigned int*)mask, mode);

    transpose_w_kernel<<<dim3(kHid / 32, kIn / 32), dim3(32, 8), 0, stream>>>(W_in, Wt_in, kIn, kHid);
    transpose_w_kernel<<<dim3(kHid / 32, kHid / 32), dim3(32, 8), 0, stream>>>(Wq, Wt_qkv, kHid, kHid);
    transpose_w_kernel<<<dim3(kHid / 32, kHid / 32), dim3(32, 8), 0, stream>>>(Wk, Wt_qkv + (size_t)kHid * kHid, kHid, kHid);
    transpose_w_kernel<<<dim3(kHid / 32, kHid / 32), dim3(32, 8), 0, stream>>>(Wv, Wt_qkv + (size_t)2 * kHid * kHid, kHid, kHid);
    transpose_w_kernel<<<dim3(kHid / 32, kHid / 32), dim3(32, 8), 0, stream>>>(Wo, Wt_o, kHid, kHid);
    concat_bias_kernel<<<6, 256, 0, stream>>>(bq, bk, bv, bqkv);

    // x = node @ W_in + b_in
    gemm_kernel<false, 1><<<dim3(kN / 128, kHid / 128), 256, 0, stream>>>(
        node, Wt_in, b_in, x, nullptr, kN, kHid, kIn, kHid);
    // fused QKV: q,k -> qkbuf[4096][1024]; v -> vt[512][4096]
    gemm_kernel<true, 3><<<dim3(kN / 128, 1536 / 128), 256, 0, stream>>>(
        x, Wt_qkv, bqkv, qkbuf, vt, kN, 1536, kHid, 1024);

    const int KZ = kN / NZ;
    attn_kernel<<<dim3(kN / 32, NZ), 512, 0, stream>>>(
        qkbuf, vt, mask, tb, mode, Op, Mp, Lp, KZ, KZ / 128);
    combine_kernel<<<(kN * kHid) / 256, 256, 0, stream>>>(Op, Mp, Lp, xo, NZ);

    // out = xo @ Wo + bo
    gemm_kernel<true, 0><<<dim3(kN / 128, kHid / 128), 256, 0, stream>>>(
        xo, Wt_o, bo, d_out, nullptr, kN, kHid, kHid, kHid);
}